// Round 2
// baseline (358.359 us; speedup 1.0000x reference)
//
#include <hip/hip_runtime.h>
#include <cstdint>

// bf16 fragments as 8 x short (4 VGPRs) per cdna_hip_programming.md §3
typedef __attribute__((ext_vector_type(8))) short bf16x8;
typedef __attribute__((ext_vector_type(4))) float f32x4;
typedef __attribute__((ext_vector_type(4))) uint16_t u16x4;

__device__ __forceinline__ uint16_t f2b(float f) {
  union { float f; uint32_t i; } v; v.f = f;
  return (uint16_t)((v.i + 0x7FFFu + ((v.i >> 16) & 1u)) >> 16);  // RNE
}

// async global->LDS, 16B per lane; LDS dest is wave-uniform base + lane*16
#define GLDS16(g, l) __builtin_amdgcn_global_load_lds( \
    (const __attribute__((address_space(1))) void*)(g), \
    (__attribute__((address_space(3))) void*)(l), 16, 0, 0)

// ---------------------------------------------------------------------------
// fp32 -> bf16 convert (RNE), vectorized x4
// ---------------------------------------------------------------------------
__global__ __launch_bounds__(256) void cvt_f32_bf16(
    const float* __restrict__ src, uint16_t* __restrict__ dst, int n) {
  const int i = (blockIdx.x * 256 + threadIdx.x) * 4;
  if (i + 3 < n) {
    const float4 v = *(const float4*)(src + i);
    u16x4 o;
    o.x = f2b(v.x); o.y = f2b(v.y); o.z = f2b(v.z); o.w = f2b(v.w);
    *(u16x4*)(dst + i) = o;
  }
}

// ---------------------------------------------------------------------------
// C[M,N] = A[M,K] @ B[N,K]^T + bias[N]. A,B bf16, bias fp32, fp32 accumulate.
// 128x128 block tile, 4 waves each computing 64x64 via 4x4 grid of 16x16x32.
// OUT_BF16: store bf16 (intermediate) or fp32 (final output).
// ---------------------------------------------------------------------------
template <bool OUT_BF16>
__global__ __launch_bounds__(256) void gemm_bt_bias(
    const uint16_t* __restrict__ A, const uint16_t* __restrict__ B,
    const float* __restrict__ bias, void* __restrict__ Cv,
    int M, int N, int K) {
  __shared__ uint16_t At[128 * 32];   // row-major [128][32], no pad (global_load_lds)
  __shared__ uint16_t Bt[128 * 32];
  const int tid = threadIdx.x;
  const int wave = tid >> 6, lane = tid & 63;
  const int q4 = lane >> 4, l16 = lane & 15;
  const int wm = wave >> 1, wn = wave & 1;
  const long blockM = (long)blockIdx.y * 128;
  const long blockN = (long)blockIdx.x * 128;

  f32x4 acc[4][4] = {};

  for (int k0 = 0; k0 < K; k0 += 32) {
    // stage: 128x32 bf16 = 8 KB = 8 chunks of (64 lanes x 16 B) each
#pragma unroll
    for (int c = 0; c < 2; ++c) {
      const int chunk = c * 4 + wave;        // 0..7, wave-uniform
      const int flat = chunk * 64 + lane;    // 0..511
      const int row = flat >> 2, seg = flat & 3;
      const uint16_t* ga = A + (blockM + row) * (long)K + k0 + seg * 8;
      const uint16_t* gb = B + (blockN + row) * (long)K + k0 + seg * 8;
      GLDS16(ga, &At[chunk * 512]);
      GLDS16(gb, &Bt[chunk * 512]);
    }
    __syncthreads();

    bf16x8 af[4], bfr[4];
#pragma unroll
    for (int i = 0; i < 4; ++i) {
      af[i]  = *(const bf16x8*)&At[(wm * 64 + i * 16 + l16) * 32 + q4 * 8];
      bfr[i] = *(const bf16x8*)&Bt[(wn * 64 + i * 16 + l16) * 32 + q4 * 8];
    }
#pragma unroll
    for (int i = 0; i < 4; ++i)
#pragma unroll
      for (int j = 0; j < 4; ++j)
        acc[i][j] = __builtin_amdgcn_mfma_f32_16x16x32_bf16(af[i], bfr[j], acc[i][j], 0, 0, 0);
    __syncthreads();
  }

  // epilogue: C/D layout col=lane&15, row=(lane>>4)*4+reg
#pragma unroll
  for (int j = 0; j < 4; ++j) {
    const long col = blockN + wn * 64 + j * 16 + l16;
    const float bv = bias[col];
#pragma unroll
    for (int i = 0; i < 4; ++i) {
      const long row0 = blockM + wm * 64 + i * 16 + q4 * 4;
#pragma unroll
      for (int r = 0; r < 4; ++r) {
        const float val = acc[i][j][r] + bv;
        const long idx = (row0 + r) * (long)N + col;
        if (OUT_BF16) ((uint16_t*)Cv)[idx] = f2b(val);
        else          ((float*)Cv)[idx] = val;
      }
    }
  }
}

// ---------------------------------------------------------------------------
// Flash-style causal attention. kqv layout (B,T,3C) bf16 with order K,Q,V.
// Block = 64 q-rows (4 waves x 16), K-tile = 128 keys.
// ---------------------------------------------------------------------------
__global__ __launch_bounds__(256) void attn_flash(
    const uint16_t* __restrict__ kqv, uint16_t* __restrict__ attn) {
  constexpr int T = 2048, C = 1024, C3 = 3072, D = 64;
  __shared__ uint16_t Kt[128 * 72];       // [key][d], pitch 72 (+8 pad)
  __shared__ uint16_t Vt[64 * 136];       // transposed: [d][key], pitch 136
  __shared__ uint16_t Pt[4][16 * 136];    // per-wave P round-trip, pitch 136

  const int tid = threadIdx.x;
  const int wave = tid >> 6, lane = tid & 63;
  const int q4 = lane >> 4, l16 = lane & 15;
  const int qb = blockIdx.x;              // q-block (64 rows)
  const int bh = blockIdx.y;
  const int b = bh >> 4, h = bh & 15;

  const size_t base = (size_t)b * T * C3;
  // Q fragments (A-layout): lane holds Q[q=l16][d=q4*8+j], 2 k-steps of 32
  const int qrow_frag = qb * 64 + wave * 16 + l16;
  const bf16x8 qf0 = *(const bf16x8*)&kqv[base + (size_t)qrow_frag * C3 + C + h * D + q4 * 8];
  const bf16x8 qf1 = *(const bf16x8*)&kqv[base + (size_t)qrow_frag * C3 + C + h * D + 32 + q4 * 8];

  f32x4 o[4] = {};
  float m_i[4], l_i[4];
#pragma unroll
  for (int r = 0; r < 4; ++r) { m_i[r] = -1e30f; l_i[r] = 0.f; }

  const int q0 = qb * 64 + wave * 16 + q4 * 4;          // q row for reg r = q0+r
  const int nkt = (qb * 64 + 63) / 128 + 1;             // causal tile count
  const float sc = 0.125f * 1.4426950408889634f;        // D^-0.5 * log2(e)

  for (int kt = 0; kt < nkt; ++kt) {
    const int kbase = kt * 128;
    __syncthreads();   // prev-iter LDS reads done
    // stage K row-major + V transposed; 1024 chunks of 8 bf16, 4 per thread
#pragma unroll
    for (int rr = 0; rr < 4; ++rr) {
      const int ci = rr * 256 + tid;
      const int row = ci >> 3, ch = ci & 7;
      const uint16_t* gk = &kqv[base + (size_t)(kbase + row) * C3 + h * D + ch * 8];
      *(bf16x8*)&Kt[row * 72 + ch * 8] = *(const bf16x8*)gk;
      const uint16_t* gv = &kqv[base + (size_t)(kbase + row) * C3 + 2 * C + h * D + ch * 8];
      bf16x8 vv = *(const bf16x8*)gv;
#pragma unroll
      for (int i = 0; i < 8; ++i)
        Vt[(ch * 8 + i) * 136 + row] = ((const uint16_t*)&vv)[i];
    }
    __syncthreads();

    // S = Q K^T (16 q-rows x 128 keys per wave)
    f32x4 s[8];
#pragma unroll
    for (int nk = 0; nk < 8; ++nk) {
      f32x4 z = {};
      const bf16x8 kf0 = *(const bf16x8*)&Kt[(nk * 16 + l16) * 72 + q4 * 8];
      const bf16x8 kf1 = *(const bf16x8*)&Kt[(nk * 16 + l16) * 72 + 32 + q4 * 8];
      z = __builtin_amdgcn_mfma_f32_16x16x32_bf16(qf0, kf0, z, 0, 0, 0);
      z = __builtin_amdgcn_mfma_f32_16x16x32_bf16(qf1, kf1, z, 0, 0, 0);
      s[nk] = z;
    }
    // causal mask + fold scale into log2 domain
#pragma unroll
    for (int nk = 0; nk < 8; ++nk) {
      const int key = kbase + nk * 16 + l16;
#pragma unroll
      for (int r = 0; r < 4; ++r)
        s[nk][r] = (key <= q0 + r) ? s[nk][r] * sc : -1e30f;
    }
    // online softmax per q-row (row lives on 16 lanes of one quad)
#pragma unroll
    for (int r = 0; r < 4; ++r) {
      float mv = s[0][r];
#pragma unroll
      for (int nk = 1; nk < 8; ++nk) mv = fmaxf(mv, s[nk][r]);
      for (int off = 1; off < 16; off <<= 1)
        mv = fmaxf(mv, __shfl_xor(mv, off, 64));
      const float mnew = fmaxf(m_i[r], mv);
      const float alpha = exp2f(m_i[r] - mnew);
      m_i[r] = mnew;
      float rs = 0.f;
#pragma unroll
      for (int nk = 0; nk < 8; ++nk) {
        const float p = exp2f(s[nk][r] - mnew);
        s[nk][r] = p;
        rs += p;
      }
      for (int off = 1; off < 16; off <<= 1)
        rs += __shfl_xor(rs, off, 64);
      l_i[r] = l_i[r] * alpha + rs;
#pragma unroll
      for (int d4 = 0; d4 < 4; ++d4) o[d4][r] *= alpha;
    }
    // P: C/D layout -> LDS -> A layout (m120 recipe)
#pragma unroll
    for (int nk = 0; nk < 8; ++nk)
#pragma unroll
      for (int r = 0; r < 4; ++r)
        Pt[wave][(q4 * 4 + r) * 136 + nk * 16 + l16] = f2b(s[nk][r]);
    __syncthreads();
    // O += P V : 4 k-steps of 32 keys
#pragma unroll
    for (int ks = 0; ks < 4; ++ks) {
      const bf16x8 pf = *(const bf16x8*)&Pt[wave][l16 * 136 + ks * 32 + q4 * 8];
#pragma unroll
      for (int d4 = 0; d4 < 4; ++d4) {
        const bf16x8 vf = *(const bf16x8*)&Vt[(d4 * 16 + l16) * 136 + ks * 32 + q4 * 8];
        o[d4] = __builtin_amdgcn_mfma_f32_16x16x32_bf16(pf, vf, o[d4], 0, 0, 0);
      }
    }
  }
  // epilogue: attn[b, q, h*D + d] = O / l  (bf16 intermediate)
  const size_t obase = (size_t)b * T * C;
#pragma unroll
  for (int r = 0; r < 4; ++r) {
    const float inv = 1.0f / l_i[r];
    const size_t rowoff = obase + (size_t)(q0 + r) * C + h * D;
#pragma unroll
    for (int d4 = 0; d4 < 4; ++d4)
      attn[rowoff + d4 * 16 + l16] = f2b(o[d4][r] * inv);
  }
}

extern "C" void kernel_launch(void* const* d_in, const int* in_sizes, int n_in,
                              void* d_out, int out_size, void* d_ws, size_t ws_size,
                              hipStream_t stream) {
  const float* x      = (const float*)d_in[0];  // (2,2048,1024) fp32
  const float* w_attn = (const float*)d_in[1];  // (3072,1024)  fp32
  const float* b_attn = (const float*)d_in[2];  // (3072,)      fp32
  const float* w_proj = (const float*)d_in[3];  // (1024,1024)  fp32
  const float* b_proj = (const float*)d_in[4];  // (1024,)      fp32
  float* out = (float*)d_out;                   // (2,2048,1024) fp32

  // ws layout (bf16): xb | wab | wpb | kqv | attnb  = 48 MiB total
  uint16_t* xb    = (uint16_t*)d_ws;                     // 4096*1024
  uint16_t* wab   = xb  + (size_t)4096 * 1024;           // 3072*1024
  uint16_t* wpb   = wab + (size_t)3072 * 1024;           // 1024*1024
  uint16_t* kqv   = wpb + (size_t)1024 * 1024;           // 4096*3072
  uint16_t* attnb = kqv + (size_t)4096 * 3072;           // 4096*1024

  dim3 blk(256, 1, 1);
  const int nx = 4096 * 1024, nwa = 3072 * 1024, nwp = 1024 * 1024;
  hipLaunchKernelGGL(cvt_f32_bf16, dim3(nx / 1024), blk, 0, stream, x, xb, nx);
  hipLaunchKernelGGL(cvt_f32_bf16, dim3(nwa / 1024), blk, 0, stream, w_attn, wab, nwa);
  hipLaunchKernelGGL(cvt_f32_bf16, dim3(nwp / 1024), blk, 0, stream, w_proj, wpb, nwp);

  hipLaunchKernelGGL((gemm_bt_bias<true>), dim3(3072 / 128, 4096 / 128, 1), blk, 0, stream,
                     xb, wab, b_attn, (void*)kqv, 4096, 3072, 1024);
  hipLaunchKernelGGL(attn_flash, dim3(32, 32, 1), blk, 0, stream, kqv, attnb);
  hipLaunchKernelGGL((gemm_bt_bias<false>), dim3(1024 / 128, 4096 / 128, 1), blk, 0, stream,
                     attnb, wpb, b_proj, (void*)out, 4096, 1024, 1024);
}

// Round 3
// 259.423 us; speedup vs baseline: 1.3814x; 1.3814x over previous
//
#include <hip/hip_runtime.h>
#include <cstdint>

// bf16 fragments as 8 x short (4 VGPRs) per cdna_hip_programming.md §3
typedef __attribute__((ext_vector_type(8))) short bf16x8;
typedef __attribute__((ext_vector_type(4))) float f32x4;
typedef __attribute__((ext_vector_type(4))) uint16_t u16x4;

__device__ __forceinline__ uint16_t f2b(float f) {
  union { float f; uint32_t i; } v; v.f = f;
  return (uint16_t)((v.i + 0x7FFFu + ((v.i >> 16) & 1u)) >> 16);  // RNE
}

// async global->LDS, 16B per lane; LDS dest is wave-uniform base + lane*16
#define GLDS16(g, l) __builtin_amdgcn_global_load_lds( \
    (const __attribute__((address_space(1))) void*)(g), \
    (__attribute__((address_space(3))) void*)(l), 16, 0, 0)

// ---------------------------------------------------------------------------
// fp32 -> bf16 convert (RNE), vectorized x4
// ---------------------------------------------------------------------------
__global__ __launch_bounds__(256) void cvt_f32_bf16(
    const float* __restrict__ src, uint16_t* __restrict__ dst, int n) {
  const int i = (blockIdx.x * 256 + threadIdx.x) * 4;
  if (i + 3 < n) {
    const float4 v = *(const float4*)(src + i);
    u16x4 o;
    o.x = f2b(v.x); o.y = f2b(v.y); o.z = f2b(v.z); o.w = f2b(v.w);
    *(u16x4*)(dst + i) = o;
  }
}

// ---------------------------------------------------------------------------
// C[M,N] = A[M,K] @ B[N,K]^T + bias[N]. A,B bf16, bias fp32, fp32 accumulate.
// 128x128 block tile, 4 waves each computing 64x64 via 4x4 grid of 16x16x32.
// ---------------------------------------------------------------------------
template <bool OUT_BF16>
__global__ __launch_bounds__(256) void gemm_bt_bias(
    const uint16_t* __restrict__ A, const uint16_t* __restrict__ B,
    const float* __restrict__ bias, void* __restrict__ Cv,
    int M, int N, int K) {
  __shared__ uint16_t At[128 * 32];   // row-major [128][32], no pad (global_load_lds)
  __shared__ uint16_t Bt[128 * 32];
  const int tid = threadIdx.x;
  const int wave = tid >> 6, lane = tid & 63;
  const int q4 = lane >> 4, l16 = lane & 15;
  const int wm = wave >> 1, wn = wave & 1;
  const long blockM = (long)blockIdx.y * 128;
  const long blockN = (long)blockIdx.x * 128;

  f32x4 acc[4][4] = {};

  for (int k0 = 0; k0 < K; k0 += 32) {
#pragma unroll
    for (int c = 0; c < 2; ++c) {
      const int chunk = c * 4 + wave;        // 0..7, wave-uniform
      const int flat = chunk * 64 + lane;    // 0..511
      const int row = flat >> 2, seg = flat & 3;
      const uint16_t* ga = A + (blockM + row) * (long)K + k0 + seg * 8;
      const uint16_t* gb = B + (blockN + row) * (long)K + k0 + seg * 8;
      GLDS16(ga, &At[chunk * 512]);
      GLDS16(gb, &Bt[chunk * 512]);
    }
    __syncthreads();

    bf16x8 af[4], bfr[4];
#pragma unroll
    for (int i = 0; i < 4; ++i) {
      af[i]  = *(const bf16x8*)&At[(wm * 64 + i * 16 + l16) * 32 + q4 * 8];
      bfr[i] = *(const bf16x8*)&Bt[(wn * 64 + i * 16 + l16) * 32 + q4 * 8];
    }
#pragma unroll
    for (int i = 0; i < 4; ++i)
#pragma unroll
      for (int j = 0; j < 4; ++j)
        acc[i][j] = __builtin_amdgcn_mfma_f32_16x16x32_bf16(af[i], bfr[j], acc[i][j], 0, 0, 0);
    __syncthreads();
  }

  // epilogue: C/D layout col=lane&15, row=(lane>>4)*4+reg
#pragma unroll
  for (int j = 0; j < 4; ++j) {
    const long col = blockN + wn * 64 + j * 16 + l16;
    const float bv = bias[col];
#pragma unroll
    for (int i = 0; i < 4; ++i) {
      const long row0 = blockM + wm * 64 + i * 16 + q4 * 4;
#pragma unroll
      for (int r = 0; r < 4; ++r) {
        const float val = acc[i][j][r] + bv;
        const long idx = (row0 + r) * (long)N + col;
        if (OUT_BF16) ((uint16_t*)Cv)[idx] = f2b(val);
        else          ((float*)Cv)[idx] = val;
      }
    }
  }
}

// ---------------------------------------------------------------------------
// Flash-style causal attention, S^T formulation.
// kqv layout (B,T,3C) bf16, order K,Q,V. Block = 64 q-rows (4 waves x 16).
// K-tile = 128 keys. S^T = K·Q^T so P-writes are b64 and softmax is per-lane.
// LDS: KP (Kt overlaid by Pt) + Vt (key-rotated swizzle) = 35.8 KB -> 4 blk/CU.
// ---------------------------------------------------------------------------
__global__ __launch_bounds__(256, 4) void attn_flash(
    const uint16_t* __restrict__ kqv, uint16_t* __restrict__ attn) {
  constexpr int T = 2048, C = 1024, C3 = 3072, D = 64;
  __shared__ uint16_t KP[128 * 72];   // Kt [key][d] pitch 72; Pt overlays after S3
  __shared__ uint16_t Vt[64 * 136];   // V^T [d][key'] pitch 136, key' = (key+8*(d>>3))&127

  const int tid = threadIdx.x;
  const int wave = tid >> 6, lane = tid & 63;
  const int q4 = lane >> 4, l16 = lane & 15;
  const int qb = (int)gridDim.x - 1 - (int)blockIdx.x;  // longest-first
  const int bh = blockIdx.y;
  const int b = bh >> 4, h = bh & 15;

  const size_t base = (size_t)b * T * C3;
  uint16_t* Pt = &KP[wave * 2176];    // 16 rows x 136 per wave (8704 u16 total <= 9216)

  // Q fragments (B-operand): lane holds Q[q=l16][d=q4*8+j], 2 k-steps of 32
  const int qrow_frag = qb * 64 + wave * 16 + l16;
  const bf16x8 qf0 = *(const bf16x8*)&kqv[base + (size_t)qrow_frag * C3 + C + h * D + q4 * 8];
  const bf16x8 qf1 = *(const bf16x8*)&kqv[base + (size_t)qrow_frag * C3 + C + h * D + 32 + q4 * 8];

  const int qrow = qb * 64 + wave * 16 + l16;           // this lane's q (S^T col)
  f32x4 o[4] = {};                                      // O[q=q4*4+r][d=d4*16+l16]
  float m_i = -1e30f, l_i = 0.f;                        // per-lane (q = l16-row)

  const int nkt = (qb * 64 + 63) / 128 + 1;             // causal tile count
  const float sc = 0.125f * 1.4426950408889634f;        // D^-0.5 * log2(e)

  for (int kt = 0; kt < nkt; ++kt) {
    const int kbase = kt * 128;
    __syncthreads();   // S1: prev-iter PV reads (Vt, Pt=KP) done
    // stage K rows: 128x64, pitch 72, 4 b128 per thread
#pragma unroll
    for (int rr = 0; rr < 4; ++rr) {
      const int ci = rr * 256 + tid;
      const int row = ci >> 3, ch = ci & 7;
      *(bf16x8*)&KP[row * 72 + ch * 8] =
          *(const bf16x8*)&kqv[base + (size_t)(kbase + row) * C3 + h * D + ch * 8];
    }
    // stage V transposed with key-rotation swizzle; pack key-pairs into b32
    {
      uint32_t* VtW = (uint32_t*)Vt;   // pitch 68 dwords
#pragma unroll
      for (int ss = 0; ss < 2; ++ss) {
        const int s = ss * 256 + tid;
        const int rp = s >> 3, ch = s & 7;     // row-pair 0..63, d-group 0..7
        const size_t g = base + (size_t)(kbase + 2 * rp) * C3 + 2 * C + h * D + ch * 8;
        const bf16x8 v0 = *(const bf16x8*)&kqv[g];
        const bf16x8 v1 = *(const bf16x8*)&kqv[g + C3];
        const int colw = (rp + 4 * ch) & 63;   // ((2rp + 8ch)&127)/2
#pragma unroll
        for (int i = 0; i < 8; ++i) {
          const uint32_t pack = (uint32_t)(uint16_t)((const short*)&v0)[i] |
                                ((uint32_t)(uint16_t)((const short*)&v1)[i] << 16);
          VtW[(ch * 8 + i) * 68 + colw] = pack;
        }
      }
    }
    __syncthreads();   // S2: staging visible

    // S^T = K·Q^T : lane holds S^T[key=q4*4+r (+16nk)][q=l16]
    f32x4 s[8];
#pragma unroll
    for (int nk = 0; nk < 8; ++nk) {
      f32x4 z = {};
      const bf16x8 kf0 = *(const bf16x8*)&KP[(nk * 16 + l16) * 72 + q4 * 8];
      const bf16x8 kf1 = *(const bf16x8*)&KP[(nk * 16 + l16) * 72 + 32 + q4 * 8];
      z = __builtin_amdgcn_mfma_f32_16x16x32_bf16(kf0, qf0, z, 0, 0, 0);
      z = __builtin_amdgcn_mfma_f32_16x16x32_bf16(kf1, qf1, z, 0, 0, 0);
      s[nk] = z;
    }
    // causal mask + scale (log2 domain)
#pragma unroll
    for (int nk = 0; nk < 8; ++nk) {
      const int key0 = kbase + nk * 16 + q4 * 4;
#pragma unroll
      for (int r = 0; r < 4; ++r)
        s[nk][r] = (key0 + r <= qrow) ? s[nk][r] * sc : -1e30f;
    }
    // online softmax: per-lane over 32 keys, then xor-16/32 across q4 groups
    float mloc = s[0][0];
#pragma unroll
    for (int nk = 0; nk < 8; ++nk)
#pragma unroll
      for (int r = 0; r < 4; ++r) mloc = fmaxf(mloc, s[nk][r]);
    mloc = fmaxf(mloc, __shfl_xor(mloc, 16, 64));
    mloc = fmaxf(mloc, __shfl_xor(mloc, 32, 64));
    const float mnew = fmaxf(m_i, mloc);
    const float alpha = exp2f(m_i - mnew);
    m_i = mnew;
    float rs = 0.f;
#pragma unroll
    for (int nk = 0; nk < 8; ++nk)
#pragma unroll
      for (int r = 0; r < 4; ++r) {
        const float p = exp2f(s[nk][r] - mnew);
        s[nk][r] = p;
        rs += p;
      }
    rs += __shfl_xor(rs, 16, 64);
    rs += __shfl_xor(rs, 32, 64);
    l_i = l_i * alpha + rs;
    // rescale O rows: alpha for q = q4*4+r fetched from lane (q4*4+r)
#pragma unroll
    for (int r = 0; r < 4; ++r) {
      const float ar = __shfl(alpha, q4 * 4 + r, 64);
#pragma unroll
      for (int d4 = 0; d4 < 4; ++d4) o[d4][r] *= ar;
    }
    __syncthreads();   // S3: all Kt reads done -> Pt may overwrite KP
    // write P row q=l16, keys nk*16+q4*4..+3 : one b64 per nk
#pragma unroll
    for (int nk = 0; nk < 8; ++nk) {
      uint32_t lo = (uint32_t)f2b(s[nk][0]) | ((uint32_t)f2b(s[nk][1]) << 16);
      uint32_t hi = (uint32_t)f2b(s[nk][2]) | ((uint32_t)f2b(s[nk][3]) << 16);
      uint2 pk; pk.x = lo; pk.y = hi;
      *(uint2*)&Pt[l16 * 136 + nk * 16 + q4 * 4] = pk;
    }
    __syncthreads();   // S4: Pt visible
    // O += P·V : A = P[q][key] row-major, B = V^T (rotated)
#pragma unroll
    for (int ks = 0; ks < 4; ++ks) {
      const bf16x8 pf = *(const bf16x8*)&Pt[l16 * 136 + ks * 32 + q4 * 8];
#pragma unroll
      for (int d4 = 0; d4 < 4; ++d4) {
        const int d = d4 * 16 + l16;
        const int col = (ks * 32 + q4 * 8 + (d >> 3) * 8) & 127;
        const bf16x8 vf = *(const bf16x8*)&Vt[d * 136 + col];
        o[d4] = __builtin_amdgcn_mfma_f32_16x16x32_bf16(pf, vf, o[d4], 0, 0, 0);
      }
    }
  }
  // epilogue: attn[b, q, h*D + d] = O / l ; l for q=q4*4+r from lane (q4*4+r)
  const size_t obase = (size_t)b * T * C;
  const float linv = 1.0f / l_i;
#pragma unroll
  for (int r = 0; r < 4; ++r) {
    const float lr = __shfl(linv, q4 * 4 + r, 64);
    const int q = qb * 64 + wave * 16 + q4 * 4 + r;
    const size_t rowoff = obase + (size_t)q * C + h * D;
#pragma unroll
    for (int d4 = 0; d4 < 4; ++d4)
      attn[rowoff + d4 * 16 + l16] = f2b(o[d4][r] * lr);
  }
}

extern "C" void kernel_launch(void* const* d_in, const int* in_sizes, int n_in,
                              void* d_out, int out_size, void* d_ws, size_t ws_size,
                              hipStream_t stream) {
  const float* x      = (const float*)d_in[0];  // (2,2048,1024) fp32
  const float* w_attn = (const float*)d_in[1];  // (3072,1024)  fp32
  const float* b_attn = (const float*)d_in[2];  // (3072,)      fp32
  const float* w_proj = (const float*)d_in[3];  // (1024,1024)  fp32
  const float* b_proj = (const float*)d_in[4];  // (1024,)      fp32
  float* out = (float*)d_out;                   // (2,2048,1024) fp32

  // ws layout (bf16): xb | wab | wpb | kqv | attnb
  uint16_t* xb    = (uint16_t*)d_ws;                     // 4096*1024
  uint16_t* wab   = xb  + (size_t)4096 * 1024;           // 3072*1024
  uint16_t* wpb   = wab + (size_t)3072 * 1024;           // 1024*1024
  uint16_t* kqv   = wpb + (size_t)1024 * 1024;           // 4096*3072
  uint16_t* attnb = kqv + (size_t)4096 * 3072;           // 4096*1024

  dim3 blk(256, 1, 1);
  const int nx = 4096 * 1024, nwa = 3072 * 1024, nwp = 1024 * 1024;
  hipLaunchKernelGGL(cvt_f32_bf16, dim3(nx / 1024), blk, 0, stream, x, xb, nx);
  hipLaunchKernelGGL(cvt_f32_bf16, dim3(nwa / 1024), blk, 0, stream, w_attn, wab, nwa);
  hipLaunchKernelGGL(cvt_f32_bf16, dim3(nwp / 1024), blk, 0, stream, w_proj, wpb, nwp);

  hipLaunchKernelGGL((gemm_bt_bias<true>), dim3(3072 / 128, 4096 / 128, 1), blk, 0, stream,
                     xb, wab, b_attn, (void*)kqv, 4096, 3072, 1024);
  hipLaunchKernelGGL(attn_flash, dim3(32, 32, 1), blk, 0, stream, kqv, attnb);
  hipLaunchKernelGGL((gemm_bt_bias<false>), dim3(1024 / 128, 4096 / 128, 1), blk, 0, stream,
                     attnb, wpb, b_proj, (void*)out, 4096, 1024, 1024);
}

// Round 4
// 201.648 us; speedup vs baseline: 1.7771x; 1.2865x over previous
//
#include <hip/hip_runtime.h>
#include <cstdint>

// bf16 fragments as 8 x short (4 VGPRs) per cdna_hip_programming.md §3
typedef __attribute__((ext_vector_type(8))) short bf16x8;
typedef __attribute__((ext_vector_type(4))) float f32x4;
typedef __attribute__((ext_vector_type(4))) uint16_t u16x4;

__device__ __forceinline__ uint16_t f2b(float f) {
  union { float f; uint32_t i; } v; v.f = f;
  return (uint16_t)((v.i + 0x7FFFu + ((v.i >> 16) & 1u)) >> 16);  // RNE
}

// async global->LDS, 16B per lane; LDS dest is wave-uniform base + lane*16
#define GLDS16(g, l) __builtin_amdgcn_global_load_lds( \
    (const __attribute__((address_space(1))) void*)(g), \
    (__attribute__((address_space(3))) void*)(l), 16, 0, 0)

// ---------------------------------------------------------------------------
// fp32 -> bf16 convert (RNE), vectorized x4
// ---------------------------------------------------------------------------
__global__ __launch_bounds__(256) void cvt_f32_bf16(
    const float* __restrict__ src, uint16_t* __restrict__ dst, int n) {
  const int i = (blockIdx.x * 256 + threadIdx.x) * 4;
  if (i + 3 < n) {
    const float4 v = *(const float4*)(src + i);
    u16x4 o;
    o.x = f2b(v.x); o.y = f2b(v.y); o.z = f2b(v.z); o.w = f2b(v.w);
    *(u16x4*)(dst + i) = o;
  }
}

// ---------------------------------------------------------------------------
// C[M,N] = A[M,K] @ B[N,K]^T + bias[N]. A,B bf16, bias fp32, fp32 accumulate.
// BM x 128 block tile, BK=64 (two BK=32 sub-stages per barrier round).
// 4 waves, each (BM/2) x 64. Vectorized epilogue via LDS transpose.
// ---------------------------------------------------------------------------
template <int BM, bool OUT_BF16>
__global__ __launch_bounds__(256) void gemm_bt_bias(
    const uint16_t* __restrict__ A, const uint16_t* __restrict__ B,
    const float* __restrict__ bias, void* __restrict__ Cv,
    int M, int N, int K) {
  constexpr int MI = BM / 32;            // acc rows of 16
  constexpr int CA = BM / 16;            // A chunks per k-half
  constexpr int CPW = (2 * (CA + 8)) / 4;
  constexpr int CT_PITCH = OUT_BF16 ? 72 : 68;   // elems; both 16B-multiples
  constexpr size_t CT_BYTES = (size_t)4 * (BM / 2) * CT_PITCH * (OUT_BF16 ? 2 : 4);
  constexpr size_t ST_BYTES = (size_t)(2 * (BM * 32 + 4096)) * 2;
  constexpr size_t LB = CT_BYTES > ST_BYTES ? CT_BYTES : ST_BYTES;
  __shared__ alignas(16) unsigned char ldsb[LB];
  uint16_t* lds = (uint16_t*)ldsb;
  const int offB0 = BM * 32;             // u16 offsets
  const int offA1 = BM * 32 + 4096;
  const int offB1 = 2 * BM * 32 + 4096;

  const int tid = threadIdx.x;
  const int wave = tid >> 6, lane = tid & 63;
  const int q4 = lane >> 4, l16 = lane & 15;
  const int wm = wave >> 1, wn = wave & 1;
  const long blockM = (long)blockIdx.y * BM;
  const long blockN = (long)blockIdx.x * 128;

  f32x4 acc[MI][4] = {};

  for (int k0 = 0; k0 < K; k0 += 64) {
#pragma unroll
    for (int c = 0; c < CPW; ++c) {
      const int id = c * 4 + wave;       // wave-uniform
      const uint16_t* mat; long rowBase; int a, kk, off;
      if (id < CA)               { mat = A; rowBase = blockM; a = id;            kk = k0;      off = 0; }
      else if (id < CA + 8)      { mat = B; rowBase = blockN; a = id - CA;       kk = k0;      off = offB0; }
      else if (id < 2 * CA + 8)  { mat = A; rowBase = blockM; a = id - CA - 8;   kk = k0 + 32; off = offA1; }
      else                       { mat = B; rowBase = blockN; a = id - 2*CA - 8; kk = k0 + 32; off = offB1; }
      const int flat = a * 64 + lane;
      const int row = flat >> 2, seg = flat & 3;
      GLDS16(mat + (rowBase + row) * (long)K + kk + seg * 8, lds + off + a * 512);
    }
    __syncthreads();
#pragma unroll
    for (int h = 0; h < 2; ++h) {
      const uint16_t* Ah = lds + (h ? offA1 : 0);
      const uint16_t* Bh = lds + (h ? offB1 : offB0);
      bf16x8 af[MI], bfr[4];
#pragma unroll
      for (int i = 0; i < MI; ++i)
        af[i] = *(const bf16x8*)&Ah[(wm * (BM / 2) + i * 16 + l16) * 32 + q4 * 8];
#pragma unroll
      for (int j = 0; j < 4; ++j)
        bfr[j] = *(const bf16x8*)&Bh[(wn * 64 + j * 16 + l16) * 32 + q4 * 8];
#pragma unroll
      for (int i = 0; i < MI; ++i)
#pragma unroll
        for (int j = 0; j < 4; ++j)
          acc[i][j] = __builtin_amdgcn_mfma_f32_16x16x32_bf16(af[i], bfr[j], acc[i][j], 0, 0, 0);
    }
    __syncthreads();
  }

  // epilogue: acc (C/D layout: col=l16, row=q4*4+r) -> per-wave LDS tile -> vector stores
  if (OUT_BF16) {
    uint16_t* ct = lds + wave * (BM / 2) * 72;
#pragma unroll
    for (int j = 0; j < 4; ++j) {
      const float bv = bias[blockN + wn * 64 + j * 16 + l16];
#pragma unroll
      for (int i = 0; i < MI; ++i)
#pragma unroll
        for (int r = 0; r < 4; ++r)
          ct[(i * 16 + q4 * 4 + r) * 72 + j * 16 + l16] = f2b(acc[i][j][r] + bv);
    }
    __syncthreads();
    uint16_t* Cb = (uint16_t*)Cv;
#pragma unroll
    for (int st = 0; st < BM / 16; ++st) {
      const int flat = st * 64 + lane;
      const int row = flat >> 3, seg = flat & 7;
      const bf16x8 v = *(const bf16x8*)&ct[row * 72 + seg * 8];
      *(bf16x8*)&Cb[(blockM + wm * (BM / 2) + row) * (long)N + blockN + wn * 64 + seg * 8] = v;
    }
  } else {
    float* ct = (float*)ldsb + wave * (BM / 2) * 68;
#pragma unroll
    for (int j = 0; j < 4; ++j) {
      const float bv = bias[blockN + wn * 64 + j * 16 + l16];
#pragma unroll
      for (int i = 0; i < MI; ++i)
#pragma unroll
        for (int r = 0; r < 4; ++r)
          ct[(i * 16 + q4 * 4 + r) * 68 + j * 16 + l16] = acc[i][j][r] + bv;
    }
    __syncthreads();
    float* Cb = (float*)Cv;
#pragma unroll
    for (int st = 0; st < BM / 8; ++st) {
      const int flat = st * 64 + lane;
      const int row = flat >> 4, seg = flat & 15;
      const f32x4 v = *(const f32x4*)&ct[row * 68 + seg * 4];
      *(f32x4*)&Cb[(blockM + wm * (BM / 2) + row) * (long)N + blockN + wn * 64 + seg * 4] = v;
    }
  }
}

// ---------------------------------------------------------------------------
// Flash-style causal attention, S^T formulation.
// Grid: 1024 1-D blocks; (qb,bh) swizzled so blocks {c, c+256, c+512, c+768}
// (same CU under round-robin dispatch) sum to exactly 34 tiles of work.
// Block = 64 q-rows (4 waves x 16). K-tile = 128 keys. P overlays Kt.
// ---------------------------------------------------------------------------
__global__ __launch_bounds__(256, 4) void attn_flash(
    const uint16_t* __restrict__ kqv, uint16_t* __restrict__ attn) {
  constexpr int T = 2048, C = 1024, C3 = 3072, D = 64;
  __shared__ uint16_t KP[128 * 72];   // Kt [key][d] pitch 72; Pt overlays after S3
  __shared__ uint16_t Vt[64 * 136];   // V^T [d][key'] pitch 136, key' = (key+16*(d>>3))&127

  const int tid = threadIdx.x;
  const int wave = tid >> 6, lane = tid & 63;
  const int q4 = lane >> 4, l16 = lane & 15;
  // load-balance swizzle: qb = r*8 + (r odd ? 7-u : u) -> per-CU tile sum == 34
  const int bi = blockIdx.x;
  const int r4 = bi >> 8, jj = bi & 255;
  const int bh = jj & 31, u = jj >> 5;
  const int qb = r4 * 8 + ((r4 & 1) ? 7 - u : u);
  const int b = bh >> 4, h = bh & 15;

  const size_t base = (size_t)b * T * C3;
  uint16_t* Pt = &KP[wave * 2176];    // 16 rows x 136 per wave

  // Q fragments (B-operand): lane holds Q[q=l16][d=q4*8+j], 2 k-steps of 32
  const int qrow_frag = qb * 64 + wave * 16 + l16;
  const bf16x8 qf0 = *(const bf16x8*)&kqv[base + (size_t)qrow_frag * C3 + C + h * D + q4 * 8];
  const bf16x8 qf1 = *(const bf16x8*)&kqv[base + (size_t)qrow_frag * C3 + C + h * D + 32 + q4 * 8];

  const int qrow = qb * 64 + wave * 16 + l16;           // this lane's q (S^T col)
  f32x4 o[4] = {};                                      // O[q=q4*4+r][d=d4*16+l16]
  float m_i = -1e30f, l_i = 0.f;                        // scaled-log2 domain

  const int nkt = (qb * 64 + 63) / 128 + 1;             // causal tile count
  const float sc = 0.125f * 1.4426950408889634f;        // D^-0.5 * log2(e)

  for (int kt = 0; kt < nkt; ++kt) {
    const int kbase = kt * 128;
    __syncthreads();   // S1: prev-iter PV reads (Vt, Pt=KP) done
    // stage K rows: 128x64, pitch 72, 4 b128 per thread
#pragma unroll
    for (int rr = 0; rr < 4; ++rr) {
      const int ci = rr * 256 + tid;
      const int row = ci >> 3, ch = ci & 7;
      *(bf16x8*)&KP[row * 72 + ch * 8] =
          *(const bf16x8*)&kqv[base + (size_t)(kbase + row) * C3 + h * D + ch * 8];
    }
    // stage V transposed, key-rotation-16 swizzle (conflict-free b32 writes)
    {
      uint32_t* VtW = (uint32_t*)Vt;   // pitch 68 dwords
#pragma unroll
      for (int ss = 0; ss < 2; ++ss) {
        const int s = ss * 256 + tid;
        const int rp = s >> 3, ch = s & 7;     // row-pair 0..63, d-group 0..7
        const size_t g = base + (size_t)(kbase + 2 * rp) * C3 + 2 * C + h * D + ch * 8;
        const bf16x8 v0 = *(const bf16x8*)&kqv[g];
        const bf16x8 v1 = *(const bf16x8*)&kqv[g + C3];
        const int colw = (rp + 8 * ch) & 63;   // dword col; key'=(key+16*(d>>3))&127
#pragma unroll
        for (int i = 0; i < 8; ++i) {
          const uint32_t pack = (uint32_t)(uint16_t)((const short*)&v0)[i] |
                                ((uint32_t)(uint16_t)((const short*)&v1)[i] << 16);
          VtW[(ch * 8 + i) * 68 + colw] = pack;
        }
      }
    }
    __syncthreads();   // S2: staging visible

    // S^T = K·Q^T : lane holds S^T[key=q4*4+r (+16nk)][q=l16]
    f32x4 s[8];
#pragma unroll
    for (int nk = 0; nk < 8; ++nk) {
      f32x4 z = {};
      const bf16x8 kf0 = *(const bf16x8*)&KP[(nk * 16 + l16) * 72 + q4 * 8];
      const bf16x8 kf1 = *(const bf16x8*)&KP[(nk * 16 + l16) * 72 + 32 + q4 * 8];
      z = __builtin_amdgcn_mfma_f32_16x16x32_bf16(kf0, qf0, z, 0, 0, 0);
      z = __builtin_amdgcn_mfma_f32_16x16x32_bf16(kf1, qf1, z, 0, 0, 0);
      s[nk] = z;
    }
    // causal mask only on the diagonal tile (wave-uniform branch)
    if (kbase + 127 > qb * 64 + wave * 16) {
#pragma unroll
      for (int nk = 0; nk < 8; ++nk) {
        const int key0 = kbase + nk * 16 + q4 * 4;
#pragma unroll
        for (int r = 0; r < 4; ++r)
          s[nk][r] = (key0 + r <= qrow) ? s[nk][r] : -1e30f;
      }
    }
    // online softmax (raw max; scale folded into exp2 via fma)
    float mloc = s[0][0];
#pragma unroll
    for (int nk = 0; nk < 8; ++nk)
#pragma unroll
      for (int r = 0; r < 4; ++r) mloc = fmaxf(mloc, s[nk][r]);
    mloc = fmaxf(mloc, __shfl_xor(mloc, 16, 64));
    mloc = fmaxf(mloc, __shfl_xor(mloc, 32, 64));
    const float mnew = fmaxf(m_i, mloc * sc);
    const float alpha = exp2f(m_i - mnew);
    m_i = mnew;
    float rs = 0.f;
#pragma unroll
    for (int nk = 0; nk < 8; ++nk)
#pragma unroll
      for (int r = 0; r < 4; ++r) {
        const float p = exp2f(fmaf(s[nk][r], sc, -mnew));
        s[nk][r] = p;
        rs += p;
      }
    rs += __shfl_xor(rs, 16, 64);
    rs += __shfl_xor(rs, 32, 64);
    l_i = l_i * alpha + rs;
    // rescale O rows: alpha for q = q4*4+r fetched from lane (q4*4+r)
#pragma unroll
    for (int r = 0; r < 4; ++r) {
      const float ar = __shfl(alpha, q4 * 4 + r, 64);
#pragma unroll
      for (int d4 = 0; d4 < 4; ++d4) o[d4][r] *= ar;
    }
    __syncthreads();   // S3: all Kt reads done -> Pt may overwrite KP
    // write P row q=l16, keys nk*16+q4*4..+3 : one b64 per nk
#pragma unroll
    for (int nk = 0; nk < 8; ++nk) {
      uint32_t lo = (uint32_t)f2b(s[nk][0]) | ((uint32_t)f2b(s[nk][1]) << 16);
      uint32_t hi = (uint32_t)f2b(s[nk][2]) | ((uint32_t)f2b(s[nk][3]) << 16);
      uint2 pk; pk.x = lo; pk.y = hi;
      *(uint2*)&Pt[l16 * 136 + nk * 16 + q4 * 4] = pk;
    }
    __syncthreads();   // S4: Pt visible
    // O += P·V : A = P[q][key] row-major, B = V^T (rotated by 16)
#pragma unroll
    for (int ks = 0; ks < 4; ++ks) {
      const bf16x8 pf = *(const bf16x8*)&Pt[l16 * 136 + ks * 32 + q4 * 8];
#pragma unroll
      for (int d4 = 0; d4 < 4; ++d4) {
        const int d = d4 * 16 + l16;
        const int col = (ks * 32 + q4 * 8 + 16 * (d >> 3)) & 127;
        const bf16x8 vf = *(const bf16x8*)&Vt[d * 136 + col];
        o[d4] = __builtin_amdgcn_mfma_f32_16x16x32_bf16(pf, vf, o[d4], 0, 0, 0);
      }
    }
  }
  // epilogue: attn[b, q, h*D + d] = O / l ; l for q=q4*4+r from lane (q4*4+r)
  const size_t obase = (size_t)b * T * C;
  const float linv = 1.0f / l_i;
#pragma unroll
  for (int r = 0; r < 4; ++r) {
    const float lr = __shfl(linv, q4 * 4 + r, 64);
    const int q = qb * 64 + wave * 16 + q4 * 4 + r;
    const size_t rowoff = obase + (size_t)q * C + h * D;
#pragma unroll
    for (int d4 = 0; d4 < 4; ++d4)
      attn[rowoff + d4 * 16 + l16] = f2b(o[d4][r] * lr);
  }
}

extern "C" void kernel_launch(void* const* d_in, const int* in_sizes, int n_in,
                              void* d_out, int out_size, void* d_ws, size_t ws_size,
                              hipStream_t stream) {
  const float* x      = (const float*)d_in[0];  // (2,2048,1024) fp32
  const float* w_attn = (const float*)d_in[1];  // (3072,1024)  fp32
  const float* b_attn = (const float*)d_in[2];  // (3072,)      fp32
  const float* w_proj = (const float*)d_in[3];  // (1024,1024)  fp32
  const float* b_proj = (const float*)d_in[4];  // (1024,)      fp32
  float* out = (float*)d_out;                   // (2,2048,1024) fp32

  // ws layout (bf16): xb | wab | wpb | kqv | attnb
  uint16_t* xb    = (uint16_t*)d_ws;                     // 4096*1024
  uint16_t* wab   = xb  + (size_t)4096 * 1024;           // 3072*1024
  uint16_t* wpb   = wab + (size_t)3072 * 1024;           // 1024*1024
  uint16_t* kqv   = wpb + (size_t)1024 * 1024;           // 4096*3072
  uint16_t* attnb = kqv + (size_t)4096 * 3072;           // 4096*1024

  dim3 blk(256, 1, 1);
  const int nx = 4096 * 1024, nwa = 3072 * 1024, nwp = 1024 * 1024;
  hipLaunchKernelGGL(cvt_f32_bf16, dim3(nx / 1024), blk, 0, stream, x, xb, nx);
  hipLaunchKernelGGL(cvt_f32_bf16, dim3(nwa / 1024), blk, 0, stream, w_attn, wab, nwa);
  hipLaunchKernelGGL(cvt_f32_bf16, dim3(nwp / 1024), blk, 0, stream, w_proj, wpb, nwp);

  hipLaunchKernelGGL((gemm_bt_bias<128, true>), dim3(3072 / 128, 4096 / 128, 1), blk, 0, stream,
                     xb, wab, b_attn, (void*)kqv, 4096, 3072, 1024);
  hipLaunchKernelGGL(attn_flash, dim3(1024, 1, 1), blk, 0, stream, kqv, attnb);
  hipLaunchKernelGGL((gemm_bt_bias<64, false>), dim3(1024 / 128, 4096 / 64, 1), blk, 0, stream,
                     attnb, wpb, b_proj, (void*)out, 4096, 1024, 1024);
}

// Round 5
// 193.563 us; speedup vs baseline: 1.8514x; 1.0418x over previous
//
#include <hip/hip_runtime.h>
#include <hip/hip_bf16.h>
#include <cstdint>

// bf16 fragments as 8 x short (4 VGPRs) per cdna_hip_programming.md §3
typedef __attribute__((ext_vector_type(8))) short bf16x8;
typedef __attribute__((ext_vector_type(4))) float f32x4;
typedef __attribute__((ext_vector_type(4))) uint16_t u16x4;

__device__ __forceinline__ uint16_t f2b(float f) {
  union { float f; uint32_t i; } v; v.f = f;
  return (uint16_t)((v.i + 0x7FFFu + ((v.i >> 16) & 1u)) >> 16);  // RNE
}

// async global->LDS, 16B per lane; LDS dest is wave-uniform base + lane*16
#define GLDS16(g, l) __builtin_amdgcn_global_load_lds( \
    (const __attribute__((address_space(1))) void*)(g), \
    (__attribute__((address_space(3))) void*)(l), 16, 0, 0)

// ---------------------------------------------------------------------------
// fp32 -> bf16 convert (RNE) for all three inputs in one launch
// ---------------------------------------------------------------------------
__global__ __launch_bounds__(256) void cvt_all(
    const float* __restrict__ x, const float* __restrict__ wa, const float* __restrict__ wp,
    uint16_t* __restrict__ xb, uint16_t* __restrict__ wab, uint16_t* __restrict__ wpb) {
  const int i = (blockIdx.x * 256 + threadIdx.x) * 4;
  const float* src; uint16_t* dst; int off;
  if (i < 4194304)      { src = x;  dst = xb;  off = i; }
  else if (i < 7340032) { src = wa; dst = wab; off = i - 4194304; }
  else                  { src = wp; dst = wpb; off = i - 7340032; }
  const float4 v = *(const float4*)(src + off);
  u16x4 o;
  o.x = f2b(v.x); o.y = f2b(v.y); o.z = f2b(v.z); o.w = f2b(v.w);
  *(u16x4*)(dst + off) = o;
}

// ---------------------------------------------------------------------------
// C[M,N] = A[M,K] @ B[N,K]^T + bias[N]. A,B bf16, bias fp32, fp32 accumulate.
// BM x 128 block tile, BK=64 (two BK=32 sub-stages per barrier round).
// 4 waves, each (BM/2) x 64. Vectorized epilogue via LDS transpose.
// ---------------------------------------------------------------------------
template <int BM, bool OUT_BF16>
__global__ __launch_bounds__(256) void gemm_bt_bias(
    const uint16_t* __restrict__ A, const uint16_t* __restrict__ B,
    const float* __restrict__ bias, void* __restrict__ Cv,
    int M, int N, int K) {
  constexpr int MI = BM / 32;            // acc rows of 16
  constexpr int CA = BM / 16;            // A chunks per k-half
  constexpr int CPW = (2 * (CA + 8)) / 4;
  constexpr int CT_PITCH = OUT_BF16 ? 72 : 68;
  constexpr size_t CT_BYTES = (size_t)4 * (BM / 2) * CT_PITCH * (OUT_BF16 ? 2 : 4);
  constexpr size_t ST_BYTES = (size_t)(2 * (BM * 32 + 4096)) * 2;
  constexpr size_t LB = CT_BYTES > ST_BYTES ? CT_BYTES : ST_BYTES;
  __shared__ alignas(16) unsigned char ldsb[LB];
  uint16_t* lds = (uint16_t*)ldsb;
  const int offB0 = BM * 32;             // u16 offsets
  const int offA1 = BM * 32 + 4096;
  const int offB1 = 2 * BM * 32 + 4096;

  const int tid = threadIdx.x;
  const int wave = tid >> 6, lane = tid & 63;
  const int q4 = lane >> 4, l16 = lane & 15;
  const int wm = wave >> 1, wn = wave & 1;
  const long blockM = (long)blockIdx.y * BM;
  const long blockN = (long)blockIdx.x * 128;

  f32x4 acc[MI][4] = {};

  for (int k0 = 0; k0 < K; k0 += 64) {
#pragma unroll
    for (int c = 0; c < CPW; ++c) {
      const int id = c * 4 + wave;       // wave-uniform
      const uint16_t* mat; long rowBase; int a, kk, off;
      if (id < CA)               { mat = A; rowBase = blockM; a = id;            kk = k0;      off = 0; }
      else if (id < CA + 8)      { mat = B; rowBase = blockN; a = id - CA;       kk = k0;      off = offB0; }
      else if (id < 2 * CA + 8)  { mat = A; rowBase = blockM; a = id - CA - 8;   kk = k0 + 32; off = offA1; }
      else                       { mat = B; rowBase = blockN; a = id - 2*CA - 8; kk = k0 + 32; off = offB1; }
      const int flat = a * 64 + lane;
      const int row = flat >> 2, seg = flat & 3;
      GLDS16(mat + (rowBase + row) * (long)K + kk + seg * 8, lds + off + a * 512);
    }
    __syncthreads();
#pragma unroll
    for (int h = 0; h < 2; ++h) {
      const uint16_t* Ah = lds + (h ? offA1 : 0);
      const uint16_t* Bh = lds + (h ? offB1 : offB0);
      bf16x8 af[MI], bfr[4];
#pragma unroll
      for (int i = 0; i < MI; ++i)
        af[i] = *(const bf16x8*)&Ah[(wm * (BM / 2) + i * 16 + l16) * 32 + q4 * 8];
#pragma unroll
      for (int j = 0; j < 4; ++j)
        bfr[j] = *(const bf16x8*)&Bh[(wn * 64 + j * 16 + l16) * 32 + q4 * 8];
#pragma unroll
      for (int i = 0; i < MI; ++i)
#pragma unroll
        for (int j = 0; j < 4; ++j)
          acc[i][j] = __builtin_amdgcn_mfma_f32_16x16x32_bf16(af[i], bfr[j], acc[i][j], 0, 0, 0);
    }
    __syncthreads();
  }

  // epilogue: acc (C/D layout: col=l16, row=q4*4+r) -> per-wave LDS tile -> vector stores
  if (OUT_BF16) {
    uint16_t* ct = lds + wave * (BM / 2) * 72;
#pragma unroll
    for (int j = 0; j < 4; ++j) {
      const float bv = bias[blockN + wn * 64 + j * 16 + l16];
#pragma unroll
      for (int i = 0; i < MI; ++i)
#pragma unroll
        for (int r = 0; r < 4; ++r)
          ct[(i * 16 + q4 * 4 + r) * 72 + j * 16 + l16] = f2b(acc[i][j][r] + bv);
    }
    __syncthreads();
    uint16_t* Cb = (uint16_t*)Cv;
#pragma unroll
    for (int st = 0; st < BM / 16; ++st) {
      const int flat = st * 64 + lane;
      const int row = flat >> 3, seg = flat & 7;
      const bf16x8 v = *(const bf16x8*)&ct[row * 72 + seg * 8];
      *(bf16x8*)&Cb[(blockM + wm * (BM / 2) + row) * (long)N + blockN + wn * 64 + seg * 8] = v;
    }
  } else {
    float* ct = (float*)ldsb + wave * (BM / 2) * 68;
#pragma unroll
    for (int j = 0; j < 4; ++j) {
      const float bv = bias[blockN + wn * 64 + j * 16 + l16];
#pragma unroll
      for (int i = 0; i < MI; ++i)
#pragma unroll
        for (int r = 0; r < 4; ++r)
          ct[(i * 16 + q4 * 4 + r) * 68 + j * 16 + l16] = acc[i][j][r] + bv;
    }
    __syncthreads();
    float* Cb = (float*)Cv;
#pragma unroll
    for (int st = 0; st < BM / 8; ++st) {
      const int flat = st * 64 + lane;
      const int row = flat >> 4, seg = flat & 15;
      const f32x4 v = *(const f32x4*)&ct[row * 68 + seg * 4];
      *(f32x4*)&Cb[(blockM + wm * (BM / 2) + row) * (long)N + blockN + wn * 64 + seg * 4] = v;
    }
  }
}

// ---------------------------------------------------------------------------
// Flash-style causal attention, S^T formulation, paired strips for uniform work.
// Grid: 512 blocks; block (p,bh) processes q-strips (31-p) then (p): exactly
// 17 K-tiles total. 2 blocks/CU steady. Next tile's K/V prefetched into VGPRs.
// ---------------------------------------------------------------------------
__global__ __launch_bounds__(256, 2) void attn_flash(
    const uint16_t* __restrict__ kqv, uint16_t* __restrict__ attn) {
  constexpr int T = 2048, C = 1024, C3 = 3072;
  __shared__ uint16_t KP[128 * 72];   // Kt [key][d] pitch 72; Pt overlays after S3
  __shared__ uint16_t Vt[64 * 136];   // V^T [d][key'] pitch 136, key' = (key+16*(d>>3))&127
  uint32_t* VtW = (uint32_t*)Vt;      // pitch 68 dwords

  const int tid = threadIdx.x;
  const int wave = tid >> 6, lane = tid & 63;
  const int q4 = lane >> 4, l16 = lane & 15;
  const int p = blockIdx.x >> 5, bh = blockIdx.x & 31;
  const int b = bh >> 4, h = bh & 15;
  const size_t base = (size_t)b * T * C3;
  const int hD = h * 64;

  uint16_t* Pt = &KP[wave * 2176];    // 16 x 136 per wave

  // loop-invariant staging coords
  const int tr = tid >> 3, kch = tid & 7;
  const float sc = 0.125f * 1.4426950408889634f;  // D^-0.5 * log2(e)

  for (int ss = 0; ss < 2; ++ss) {
    const int qb = ss ? p : 31 - p;
    const int nkt = (qb >> 1) + 1;
    const int qrow = qb * 64 + wave * 16 + l16;
    const bf16x8 qf0 = *(const bf16x8*)&kqv[base + (size_t)qrow * C3 + C + hD + q4 * 8];
    const bf16x8 qf1 = *(const bf16x8*)&kqv[base + (size_t)qrow * C3 + C + hD + 32 + q4 * 8];

    f32x4 o[4] = {};                  // O[q=q4*4+r][d=d4*16+l16]
    float m_i = -1e30f, l_i = 0.f;

    // prefetch tile 0 into VGPRs
    bf16x8 pk[4], pv0[2], pv1[2];
#pragma unroll
    for (int rr = 0; rr < 4; ++rr)
      pk[rr] = *(const bf16x8*)&kqv[base + (size_t)(rr * 32 + tr) * C3 + hD + kch * 8];
#pragma unroll
    for (int s2 = 0; s2 < 2; ++s2) {
      const size_t g = base + (size_t)(2 * (s2 * 32 + tr)) * C3 + 2 * C + hD + kch * 8;
      pv0[s2] = *(const bf16x8*)&kqv[g];
      pv1[s2] = *(const bf16x8*)&kqv[g + C3];
    }

    for (int kt = 0; kt < nkt; ++kt) {
      const int kbase = kt * 128;
      __syncthreads();   // S1: prior PV reads / prior strip done
      // stage K from prefetch regs (b128, LDS addr loop-invariant)
#pragma unroll
      for (int rr = 0; rr < 4; ++rr)
        *(bf16x8*)&KP[(rr * 32 + tr) * 72 + kch * 8] = pk[rr];
      // stage V transposed: v_perm pack key-pairs, rot-16 swizzle (2-way free)
#pragma unroll
      for (int s2 = 0; s2 < 2; ++s2) {
        const int colw = ((s2 * 32 + tr) + 8 * kch) & 63;
        const uint32_t* a0 = (const uint32_t*)&pv0[s2];
        const uint32_t* a1 = (const uint32_t*)&pv1[s2];
#pragma unroll
        for (int i = 0; i < 8; ++i) {
          const uint32_t w = (i & 1)
              ? __builtin_amdgcn_perm(a1[i >> 1], a0[i >> 1], 0x07060302u)
              : __builtin_amdgcn_perm(a1[i >> 1], a0[i >> 1], 0x05040100u);
          VtW[(kch * 8 + i) * 68 + colw] = w;
        }
      }
      __syncthreads();   // S2: staging visible
      // prefetch next tile (loads in flight across the compute phase)
      if (kt + 1 < nkt) {
        const int kb = kbase + 128;
#pragma unroll
        for (int rr = 0; rr < 4; ++rr)
          pk[rr] = *(const bf16x8*)&kqv[base + (size_t)(kb + rr * 32 + tr) * C3 + hD + kch * 8];
#pragma unroll
        for (int s2 = 0; s2 < 2; ++s2) {
          const size_t g = base + (size_t)(kb + 2 * (s2 * 32 + tr)) * C3 + 2 * C + hD + kch * 8;
          pv0[s2] = *(const bf16x8*)&kqv[g];
          pv1[s2] = *(const bf16x8*)&kqv[g + C3];
        }
      }
      // S^T = K·Q^T : lane holds S^T[key=16nk+q4*4+r][q=l16]
      f32x4 s[8];
#pragma unroll
      for (int nk = 0; nk < 8; ++nk) {
        f32x4 z = {};
        const bf16x8 kf0 = *(const bf16x8*)&KP[(nk * 16 + l16) * 72 + q4 * 8];
        const bf16x8 kf1 = *(const bf16x8*)&KP[(nk * 16 + l16) * 72 + 32 + q4 * 8];
        z = __builtin_amdgcn_mfma_f32_16x16x32_bf16(kf0, qf0, z, 0, 0, 0);
        z = __builtin_amdgcn_mfma_f32_16x16x32_bf16(kf1, qf1, z, 0, 0, 0);
        s[nk] = z;
      }
      // causal mask only on diagonal tiles (wave-uniform branch)
      if (kbase + 127 > qb * 64 + wave * 16) {
#pragma unroll
        for (int nk = 0; nk < 8; ++nk) {
          const int key0 = kbase + nk * 16 + q4 * 4;
#pragma unroll
          for (int r = 0; r < 4; ++r)
            s[nk][r] = (key0 + r <= qrow) ? s[nk][r] : -1e30f;
        }
      }
      // online softmax (per-lane over 32 keys + 2 shuffles)
      float mloc = s[0][0];
#pragma unroll
      for (int nk = 0; nk < 8; ++nk)
#pragma unroll
        for (int r = 0; r < 4; ++r) mloc = fmaxf(mloc, s[nk][r]);
      mloc = fmaxf(mloc, __shfl_xor(mloc, 16, 64));
      mloc = fmaxf(mloc, __shfl_xor(mloc, 32, 64));
      const float mnew = fmaxf(m_i, mloc * sc);
      const float alpha = exp2f(m_i - mnew);
      const bool mchg = mnew > m_i;
      m_i = mnew;
      float rs = 0.f;
#pragma unroll
      for (int nk = 0; nk < 8; ++nk)
#pragma unroll
        for (int r = 0; r < 4; ++r) {
          const float pe = exp2f(fmaf(s[nk][r], sc, -mnew));
          s[nk][r] = pe;
          rs += pe;
        }
      rs += __shfl_xor(rs, 16, 64);
      rs += __shfl_xor(rs, 32, 64);
      l_i = l_i * alpha + rs;
      if (__any(mchg)) {   // skip O-rescale when every row's max is unchanged
#pragma unroll
        for (int r = 0; r < 4; ++r) {
          const float ar = __shfl(alpha, q4 * 4 + r, 64);
#pragma unroll
          for (int d4 = 0; d4 < 4; ++d4) o[d4][r] *= ar;
        }
      }
      __syncthreads();   // S3: Kt reads done -> Pt may overwrite KP
      // P write: packed bf16 pairs, one b64 per nk
#pragma unroll
      for (int nk = 0; nk < 8; ++nk) {
        union { __hip_bfloat162 h2; uint32_t u; } c01, c23;
        c01.h2 = __float22bfloat162_rn(make_float2(s[nk][0], s[nk][1]));
        c23.h2 = __float22bfloat162_rn(make_float2(s[nk][2], s[nk][3]));
        uint2 pkw; pkw.x = c01.u; pkw.y = c23.u;
        *(uint2*)&Pt[l16 * 136 + nk * 16 + q4 * 4] = pkw;
      }
      __syncthreads();   // S4: Pt visible
      // O += P·V
#pragma unroll
      for (int ks = 0; ks < 4; ++ks) {
        const bf16x8 pf = *(const bf16x8*)&Pt[l16 * 136 + ks * 32 + q4 * 8];
#pragma unroll
        for (int d4 = 0; d4 < 4; ++d4) {
          const int d = d4 * 16 + l16;
          const int col = (ks * 32 + q4 * 8 + 16 * (d >> 3)) & 127;
          const bf16x8 vf = *(const bf16x8*)&Vt[d * 136 + col];
          o[d4] = __builtin_amdgcn_mfma_f32_16x16x32_bf16(pf, vf, o[d4], 0, 0, 0);
        }
      }
    }
    // epilogue for this strip
    const size_t obase = (size_t)b * T * C;
    const float linv = 1.0f / l_i;
#pragma unroll
    for (int r = 0; r < 4; ++r) {
      const float lr = __shfl(linv, q4 * 4 + r, 64);
      const int q = qb * 64 + wave * 16 + q4 * 4 + r;
      const size_t rowoff = obase + (size_t)q * C + hD;
#pragma unroll
      for (int d4 = 0; d4 < 4; ++d4)
        attn[rowoff + d4 * 16 + l16] = f2b(o[d4][r] * lr);
    }
  }
}

extern "C" void kernel_launch(void* const* d_in, const int* in_sizes, int n_in,
                              void* d_out, int out_size, void* d_ws, size_t ws_size,
                              hipStream_t stream) {
  const float* x      = (const float*)d_in[0];  // (2,2048,1024) fp32
  const float* w_attn = (const float*)d_in[1];  // (3072,1024)  fp32
  const float* b_attn = (const float*)d_in[2];  // (3072,)      fp32
  const float* w_proj = (const float*)d_in[3];  // (1024,1024)  fp32
  const float* b_proj = (const float*)d_in[4];  // (1024,)      fp32
  float* out = (float*)d_out;                   // (2,2048,1024) fp32

  // ws layout (bf16): xb | wab | wpb | kqv | attnb
  uint16_t* xb    = (uint16_t*)d_ws;                     // 4096*1024
  uint16_t* wab   = xb  + (size_t)4096 * 1024;           // 3072*1024
  uint16_t* wpb   = wab + (size_t)3072 * 1024;           // 1024*1024
  uint16_t* kqv   = wpb + (size_t)1024 * 1024;           // 4096*3072
  uint16_t* attnb = kqv + (size_t)4096 * 3072;           // 4096*1024

  dim3 blk(256, 1, 1);
  hipLaunchKernelGGL(cvt_all, dim3(8192), blk, 0, stream, x, w_attn, w_proj, xb, wab, wpb);

  hipLaunchKernelGGL((gemm_bt_bias<128, true>), dim3(3072 / 128, 4096 / 128, 1), blk, 0, stream,
                     xb, wab, b_attn, (void*)kqv, 4096, 3072, 1024);
  hipLaunchKernelGGL(attn_flash, dim3(512, 1, 1), blk, 0, stream, kqv, attnb);
  hipLaunchKernelGGL((gemm_bt_bias<64, false>), dim3(1024 / 128, 4096 / 64, 1), blk, 0, stream,
                     attnb, wpb, b_proj, (void*)out, 4096, 1024, 1024);
}